// Round 2
// baseline (372.356 us; speedup 1.0000x reference)
//
#include <hip/hip_runtime.h>
#include <cstdint>

// ---------- problem constants ----------
constexpr int Bc  = 2;
constexpr int Sc  = 2048;
constexpr int Dc  = 1024;
constexpr int Hc  = 16;
constexpr int DKc = 64;
constexpr int DFFc= 4096;
constexpr int BSc = Bc * Sc;      // 4096 rows

typedef __attribute__((ext_vector_type(8))) short bf16x8;
typedef __attribute__((ext_vector_type(4))) float f32x4;

__device__ __forceinline__ unsigned short f2bf(float x){
  union { float f; uint32_t u; } v; v.f = x;
  uint32_t r = v.u + 0x7fffu + ((v.u >> 16) & 1u);   // RNE
  return (unsigned short)(r >> 16);
}

__device__ __forceinline__ void gload16(const void* g, void* l){
  __builtin_amdgcn_global_load_lds((const __attribute__((address_space(1))) void*)g,
                                   (__attribute__((address_space(3))) void*)l, 16, 0, 0);
}

__device__ __forceinline__ f32x4 mfma16(bf16x8 a, bf16x8 b, f32x4 c){
  return __builtin_amdgcn_mfma_f32_16x16x32_bf16(a, b, c, 0, 0, 0);
}

// ---------- weight transpose f32[K][N] -> bf16[N][K] ----------
__global__ __launch_bounds__(256)
void transpose_w(const float* __restrict__ in, unsigned short* __restrict__ out,
                 int K, int N){
  __shared__ float t[32][33];
  const int tx = threadIdx.x, ty = threadIdx.y;
  const int x0 = blockIdx.x * 32, y0 = blockIdx.y * 32;
#pragma unroll
  for (int j = ty; j < 32; j += 8) t[j][tx] = in[(long)(y0 + j) * N + x0 + tx];
  __syncthreads();
#pragma unroll
  for (int j = ty; j < 32; j += 8)
    out[(long)(x0 + j) * K + y0 + tx] = f2bf(t[tx][j]);
}

__global__ __launch_bounds__(256)
void concat_bias(const float* __restrict__ bq, const float* __restrict__ bk,
                 const float* __restrict__ bv, float* __restrict__ bqkv){
  int i = blockIdx.x * 256 + threadIdx.x;   // 0..3071
  float v = (i < 1024) ? bq[i] : (i < 2048 ? bk[i - 1024] : bv[i - 2048]);
  bqkv[i] = v;
}

// ---------- layernorm (ddof=1, eps on std, scalar alpha/beta) f32 -> bf16 ----------
__global__ __launch_bounds__(256)
void layernorm_k(const float* __restrict__ x, const float* __restrict__ al,
                 const float* __restrict__ be, unsigned short* __restrict__ out){
  const int row = blockIdx.x, tid = threadIdx.x;
  const float4 v = ((const float4*)(x + (long)row * Dc))[tid];
  float s  = v.x + v.y + v.z + v.w;
  float ss = v.x*v.x + v.y*v.y + v.z*v.z + v.w*v.w;
#pragma unroll
  for (int d = 1; d < 64; d <<= 1){ s += __shfl_xor(s, d, 64); ss += __shfl_xor(ss, d, 64); }
  __shared__ float red[8];
  const int wid = tid >> 6, lane = tid & 63;
  if (lane == 0){ red[wid*2] = s; red[wid*2+1] = ss; }
  __syncthreads();
  s  = red[0] + red[2] + red[4] + red[6];
  ss = red[1] + red[3] + red[5] + red[7];
  const float mean = s * (1.f / 1024.f);
  float var = (ss - s * mean) * (1.f / 1023.f);
  var = fmaxf(var, 0.f);
  const float k = al[0] / (sqrtf(var) + 1e-6f);
  const float g = be[0];
  ushort4 o;
  o.x = f2bf((v.x - mean) * k + g);
  o.y = f2bf((v.y - mean) * k + g);
  o.z = f2bf((v.z - mean) * k + g);
  o.w = f2bf((v.w - mean) * k + g);
  ((ushort4*)(out + (long)row * Dc))[tid] = o;
}

// ---------- GEMM: C[M][N] = A[M][K](bf16) * BT[N][K](bf16) + bias (+res)(relu) ----------
// 128x128 tile, BK=32, 4 waves (2x2), 16x16x32 bf16 MFMA, global_load_lds staging.
template<int RELU, int OUTBF16, int RES>
__global__ __launch_bounds__(256)
void gemm_bt(const unsigned short* __restrict__ A, const unsigned short* __restrict__ BT,
             const float* __restrict__ bias, const float* __restrict__ resid,
             void* __restrict__ Cout, int M, int N, int K){
  __shared__ unsigned short As[128 * 32];
  __shared__ unsigned short Bs[128 * 32];
  const int tid  = threadIdx.x;
  const int wid  = tid >> 6, lane = tid & 63;
  const int lg   = lane >> 4, lr = lane & 15;
  const int m0   = blockIdx.y * 128, n0 = blockIdx.x * 128;
  const int wr   = wid >> 1, wc = wid & 1;
  const long ldA = (long)K * 2;
  const f32x4 zero4 = {0.f, 0.f, 0.f, 0.f};
  f32x4 acc[4][4];
#pragma unroll
  for (int i = 0; i < 4; i++)
#pragma unroll
    for (int j = 0; j < 4; j++) acc[i][j] = zero4;

  for (int kt = 0; kt < K; kt += 32){
    __syncthreads();
#pragma unroll
    for (int ld = 0; ld < 2; ++ld){
      const int o  = (wid * 2 + ld) * 1024;          // 1024B per gload16 (64 lanes x 16B)
      const int ol = o + lane * 16;
      const int r  = ol >> 6, cb = ol & 63;          // row (64B per row), col-byte
      gload16((const char*)A  + (long)(m0 + r) * ldA + kt * 2 + cb, (char*)As + o);
      gload16((const char*)BT + (long)(n0 + r) * ldA + kt * 2 + cb, (char*)Bs + o);
    }
    __syncthreads();
    bf16x8 af[4], bfr[4];
#pragma unroll
    for (int mi = 0; mi < 4; mi++)
      af[mi] = *reinterpret_cast<const bf16x8*>(As + (wr*64 + mi*16 + lr) * 32 + lg * 8);
#pragma unroll
    for (int ni = 0; ni < 4; ni++)
      bfr[ni] = *reinterpret_cast<const bf16x8*>(Bs + (wc*64 + ni*16 + lr) * 32 + lg * 8);
#pragma unroll
    for (int mi = 0; mi < 4; mi++)
#pragma unroll
      for (int ni = 0; ni < 4; ni++)
        acc[mi][ni] = mfma16(af[mi], bfr[ni], acc[mi][ni]);
  }
#pragma unroll
  for (int mi = 0; mi < 4; mi++)
#pragma unroll
    for (int ni = 0; ni < 4; ni++){
      const int col = n0 + wc*64 + ni*16 + lr;
      const float bc = bias[col];
#pragma unroll
      for (int r = 0; r < 4; r++){
        const int row = m0 + wr*64 + mi*16 + lg*4 + r;
        float v = acc[mi][ni][r] + bc;
        if (RES)  v += resid[(long)row * N + col];
        if (RELU) v = fmaxf(v, 0.f);
        if (OUTBF16) ((unsigned short*)Cout)[(long)row * N + col] = f2bf(v);
        else         ((float*)Cout)[(long)row * N + col] = v;
      }
    }
}

// ---------- V transpose: qkv[.,2048+h*64+dk] -> vt[bh][dk][s] ----------
__global__ __launch_bounds__(256)
void transpose_v(const unsigned short* __restrict__ qkv, unsigned short* __restrict__ vt){
  __shared__ unsigned short tile[64][72];
  const int st = blockIdx.x * 64, bh = blockIdx.y;
  const int b = bh >> 4, h = bh & 15;
  const int tid = threadIdx.x;
  const int r = tid >> 2, c0 = (tid & 3) * 16;
  const unsigned short* src = qkv + ((long)(b*Sc + st + r) * 3072 + 2048 + h*64 + c0);
  *(uint4*)&tile[r][c0]     = *(const uint4*)src;
  *(uint4*)&tile[r][c0 + 8] = *(const uint4*)(src + 8);
  __syncthreads();
  union { unsigned short u[8]; uint4 v; } w0, w1;
#pragma unroll
  for (int j = 0; j < 8; j++){ w0.u[j] = tile[c0 + j][r]; w1.u[j] = tile[c0 + 8 + j][r]; }
  unsigned short* dst = vt + ((long)(bh*64 + r) * Sc + st + c0);
  *(uint4*)dst       = w0.v;
  *(uint4*)(dst + 8) = w1.v;
}

// ---------- flash attention: QBLK=64 (4 waves x 16 rows), KBLK=64 ----------
__global__ __launch_bounds__(256)
void attn_k(const unsigned short* __restrict__ qkv, const unsigned short* __restrict__ vt,
            const int* __restrict__ mask, unsigned short* __restrict__ ctx){
  __shared__ unsigned short Qs[64*64], Ks[64*64], Vs[64*64], Ps[4*16*64];
  const int tid = threadIdx.x, wid = tid >> 6, lane = tid & 63;
  const int lg = lane >> 4, lr = lane & 15;
  const int qt = blockIdx.x, bh = blockIdx.y;
  const int b = bh >> 4, h = bh & 15;
  const int s0 = qt * 64;
  const f32x4 zero4 = {0.f, 0.f, 0.f, 0.f};

  // stage Q (swizzled source: 16B chunk c holds global chunk c^(r&7))
  const char* qbase = (const char*)qkv + ((long)(b*Sc + s0)) * 6144 + h * 128;
#pragma unroll
  for (int ld = 0; ld < 2; ++ld){
    const int o = (wid*2 + ld) * 1024;
    const int ol = o + lane * 16;
    const int r = ol >> 7, c = (ol >> 4) & 7;
    gload16(qbase + (long)r * 6144 + ((c ^ (r & 7)) << 4), (char*)Qs + o);
  }

  float m_[4], l_[4];
  f32x4 acc[4];
#pragma unroll
  for (int i = 0; i < 4; i++){ m_[i] = -1e30f; l_[i] = 0.f; acc[i] = zero4; }

  const char* kbase = (const char*)qkv + (long)(b*Sc) * 6144 + 2048 + h * 128;
  const char* vbase = (const char*)vt + (long)bh * 64 * 4096;
  const int* mrow = mask + b * Sc;

  for (int t = 0; t < Sc / 64; ++t){
    const int k0 = t * 64;
    __syncthreads();
#pragma unroll
    for (int ld = 0; ld < 2; ++ld){
      const int o = (wid*2 + ld) * 1024;
      const int ol = o + lane * 16;
      const int r = ol >> 7, c = (ol >> 4) & 7;
      const int sw = ((c ^ (r & 7)) << 4);
      gload16(kbase + (long)(k0 + r) * 6144 + sw, (char*)Ks + o);
      gload16(vbase + (long)r * 4096 + k0 * 2 + sw, (char*)Vs + o);
    }
    __syncthreads();

    // S = Q * K^T  (per wave: 16 q-rows x 64 k-cols)
    const int qrow = wid * 16 + lr;
    bf16x8 aq[2];
#pragma unroll
    for (int ks = 0; ks < 2; ++ks)
      aq[ks] = *reinterpret_cast<const bf16x8*>(Qs + qrow*64 + (((ks*4 + lg) ^ (qrow & 7)) << 3));
    f32x4 sc4[4];
#pragma unroll
    for (int ni = 0; ni < 4; ++ni){
      sc4[ni] = zero4;
      const int krow = ni*16 + lr;
#pragma unroll
      for (int ks = 0; ks < 2; ++ks){
        bf16x8 bk8 = *reinterpret_cast<const bf16x8*>(Ks + krow*64 + (((ks*4 + lg) ^ (krow & 7)) << 3));
        sc4[ni] = mfma16(aq[ks], bk8, sc4[ni]);
      }
    }
    // scale + mask
    float sv[4][4];
#pragma unroll
    for (int ni = 0; ni < 4; ni++){
      const int col = lr + ni*16;
      const int mk = mrow[k0 + col];
#pragma unroll
      for (int r = 0; r < 4; r++)
        sv[ni][r] = (mk == 0) ? -1e9f : sc4[ni][r] * 0.125f;
    }
    // online softmax per row (row = 4*lg + r within this wave's strip)
    float scl[4];
#pragma unroll
    for (int r = 0; r < 4; r++){
      float mx = fmaxf(fmaxf(sv[0][r], sv[1][r]), fmaxf(sv[2][r], sv[3][r]));
#pragma unroll
      for (int d = 1; d < 16; d <<= 1) mx = fmaxf(mx, __shfl_xor(mx, d, 64));
      const float mnew = fmaxf(m_[r], mx);
      const float sc = __expf(m_[r] - mnew);
      m_[r] = mnew; scl[r] = sc;
      float rs = 0.f;
#pragma unroll
      for (int ni = 0; ni < 4; ni++){ float p = __expf(sv[ni][r] - mnew); sv[ni][r] = p; rs += p; }
#pragma unroll
      for (int d = 1; d < 16; d <<= 1) rs += __shfl_xor(rs, d, 64);
      l_[r] = l_[r] * sc + rs;
    }
#pragma unroll
    for (int ni = 0; ni < 4; ni++)
#pragma unroll
      for (int r = 0; r < 4; r++) acc[ni][r] *= scl[r];

    // write P strip (bf16, swizzled), then read back as A-frags
    unsigned short* pb = Ps + wid * 1024;
#pragma unroll
    for (int ni = 0; ni < 4; ni++){
      const int col = lr + ni*16;
#pragma unroll
      for (int r = 0; r < 4; r++){
        const int rr = lg*4 + r;
        pb[rr*64 + (((col >> 3) ^ (rr & 7)) << 3) + (col & 7)] = f2bf(sv[ni][r]);
      }
    }
    bf16x8 pa[2];
#pragma unroll
    for (int ks = 0; ks < 2; ++ks)
      pa[ks] = *reinterpret_cast<const bf16x8*>(pb + lr*64 + (((ks*4 + lg) ^ (lr & 7)) << 3));
#pragma unroll
    for (int ni = 0; ni < 4; ++ni){
      const int vrow = lr + ni*16;
#pragma unroll
      for (int ks = 0; ks < 2; ++ks){
        bf16x8 bv8 = *reinterpret_cast<const bf16x8*>(Vs + vrow*64 + (((ks*4 + lg) ^ (vrow & 7)) << 3));
        acc[ni] = mfma16(pa[ks], bv8, acc[ni]);
      }
    }
  }
  // epilogue: ctx = acc / l
#pragma unroll
  for (int ni = 0; ni < 4; ni++){
    const int col = h*64 + ni*16 + lr;
#pragma unroll
    for (int r = 0; r < 4; r++){
      const int row = s0 + wid*16 + lg*4 + r;
      ctx[(long)(b*Sc + row) * Dc + col] = f2bf(acc[ni][r] / l_[r]);
    }
  }
}

// ---------- host ----------
extern "C" void kernel_launch(void* const* d_in, const int* in_sizes, int n_in,
                              void* d_out, int out_size, void* d_ws, size_t ws_size,
                              hipStream_t stream){
  const float* x  = (const float*)d_in[0];
  const int* mask = (const int*)d_in[1];
  const float* wq = (const float*)d_in[2];
  const float* bq = (const float*)d_in[3];
  const float* wk = (const float*)d_in[4];
  const float* bk = (const float*)d_in[5];
  const float* wv = (const float*)d_in[6];
  const float* bv = (const float*)d_in[7];
  const float* wo = (const float*)d_in[8];
  const float* bo = (const float*)d_in[9];
  const float* w1 = (const float*)d_in[10];
  const float* b1 = (const float*)d_in[11];
  const float* w2 = (const float*)d_in[12];
  const float* b2 = (const float*)d_in[13];
  const float* a1 = (const float*)d_in[14];
  const float* g1 = (const float*)d_in[15];
  const float* a2 = (const float*)d_in[16];
  const float* g2 = (const float*)d_in[17];

  if (ws_size < 75509760u) return;   // workspace layout below needs ~75.5 MB

  char* ws = (char*)d_ws;
  unsigned short* wqkv_t = (unsigned short*)(ws + 0);          // [3072][1024]
  unsigned short* wo_t   = (unsigned short*)(ws + 6291456);    // [1024][1024]
  unsigned short* w1_t   = (unsigned short*)(ws + 8388608);    // [4096][1024]
  unsigned short* w2_t   = (unsigned short*)(ws + 16777216);   // [1024][4096]
  float*          bqkv   = (float*)(ws + 25165824);            // [3072]
  unsigned short* nbuf   = (unsigned short*)(ws + 25178112);   // [4096][1024] (n1 then n2)
  unsigned short* qkv    = (unsigned short*)(ws + 33566720);   // [4096][3072]
  unsigned short* ff1    = (unsigned short*)(ws + 33566720);   // [4096][4096] (reuses qkv+vt)
  unsigned short* vt     = (unsigned short*)(ws + 58732544);   // [32][64][2048]
  unsigned short* ctx    = (unsigned short*)(ws + 67121152);   // [4096][1024]
  float* x2 = (float*)d_out;                                   // [4096][1024] f32

  const dim3 tb(32, 8);
  transpose_w<<<dim3(32, 32),  tb, 0, stream>>>(wq, wqkv_t,            1024, 1024);
  transpose_w<<<dim3(32, 32),  tb, 0, stream>>>(wk, wqkv_t + 1048576,  1024, 1024);
  transpose_w<<<dim3(32, 32),  tb, 0, stream>>>(wv, wqkv_t + 2097152,  1024, 1024);
  transpose_w<<<dim3(32, 32),  tb, 0, stream>>>(wo, wo_t,              1024, 1024);
  transpose_w<<<dim3(128, 32), tb, 0, stream>>>(w1, w1_t,              1024, 4096);
  transpose_w<<<dim3(32, 128), tb, 0, stream>>>(w2, w2_t,              4096, 1024);
  concat_bias<<<12, 256, 0, stream>>>(bq, bk, bv, bqkv);

  layernorm_k<<<BSc, 256, 0, stream>>>(x, a1, g1, nbuf);
  gemm_bt<0,1,0><<<dim3(24, 32), 256, 0, stream>>>(nbuf, wqkv_t, bqkv, nullptr, qkv, BSc, 3072, 1024);
  transpose_v<<<dim3(32, 32), 256, 0, stream>>>(qkv, vt);
  attn_k<<<dim3(32, 32), 256, 0, stream>>>(qkv, vt, mask, ctx);
  gemm_bt<0,0,1><<<dim3(8, 32), 256, 0, stream>>>(ctx, wo_t, bo, x, x2, BSc, 1024, 1024);
  layernorm_k<<<BSc, 256, 0, stream>>>(x2, a2, g2, nbuf);
  gemm_bt<1,1,0><<<dim3(32, 32), 256, 0, stream>>>(nbuf, w1_t, b1, nullptr, ff1, BSc, 4096, 1024);
  gemm_bt<0,0,1><<<dim3(8, 32), 256, 0, stream>>>(ff1, w2_t, b2, x2, d_out, BSc, 1024, 4096);
}

// Round 3
// 346.355 us; speedup vs baseline: 1.0751x; 1.0751x over previous
//
#include <hip/hip_runtime.h>
#include <cstdint>

// ---------- problem constants ----------
constexpr int Bc  = 2;
constexpr int Sc  = 2048;
constexpr int Dc  = 1024;
constexpr int Hc  = 16;
constexpr int DKc = 64;
constexpr int DFFc= 4096;
constexpr int BSc = Bc * Sc;      // 4096 rows

typedef __attribute__((ext_vector_type(8))) short bf16x8;
typedef __attribute__((ext_vector_type(4))) float f32x4;

__device__ __forceinline__ unsigned short f2bf(float x){
  union { float f; uint32_t u; } v; v.f = x;
  uint32_t r = v.u + 0x7fffu + ((v.u >> 16) & 1u);   // RNE
  return (unsigned short)(r >> 16);
}

__device__ __forceinline__ void gload16(const void* g, void* l){
  __builtin_amdgcn_global_load_lds((const __attribute__((address_space(1))) void*)g,
                                   (__attribute__((address_space(3))) void*)l, 16, 0, 0);
}

__device__ __forceinline__ f32x4 mfma16(bf16x8 a, bf16x8 b, f32x4 c){
  return __builtin_amdgcn_mfma_f32_16x16x32_bf16(a, b, c, 0, 0, 0);
}

// ---------- weight transpose f32[K][N] -> bf16[N][K] ----------
__global__ __launch_bounds__(256)
void transpose_w(const float* __restrict__ in, unsigned short* __restrict__ out,
                 int K, int N){
  __shared__ float t[32][33];
  const int tx = threadIdx.x, ty = threadIdx.y;
  const int x0 = blockIdx.x * 32, y0 = blockIdx.y * 32;
#pragma unroll
  for (int j = ty; j < 32; j += 8) t[j][tx] = in[(long)(y0 + j) * N + x0 + tx];
  __syncthreads();
#pragma unroll
  for (int j = ty; j < 32; j += 8)
    out[(long)(x0 + j) * K + y0 + tx] = f2bf(t[tx][j]);
}

__global__ __launch_bounds__(256)
void concat_bias(const float* __restrict__ bq, const float* __restrict__ bk,
                 const float* __restrict__ bv, float* __restrict__ bqkv){
  int i = blockIdx.x * 256 + threadIdx.x;   // 0..3071
  float v = (i < 1024) ? bq[i] : (i < 2048 ? bk[i - 1024] : bv[i - 2048]);
  bqkv[i] = v;
}

// ---------- layernorm (ddof=1, eps on std, scalar alpha/beta) f32 -> bf16 ----------
__global__ __launch_bounds__(256)
void layernorm_k(const float* __restrict__ x, const float* __restrict__ al,
                 const float* __restrict__ be, unsigned short* __restrict__ out){
  const int row = blockIdx.x, tid = threadIdx.x;
  const float4 v = ((const float4*)(x + (long)row * Dc))[tid];
  float s  = v.x + v.y + v.z + v.w;
  float ss = v.x*v.x + v.y*v.y + v.z*v.z + v.w*v.w;
#pragma unroll
  for (int d = 1; d < 64; d <<= 1){ s += __shfl_xor(s, d, 64); ss += __shfl_xor(ss, d, 64); }
  __shared__ float red[8];
  const int wid = tid >> 6, lane = tid & 63;
  if (lane == 0){ red[wid*2] = s; red[wid*2+1] = ss; }
  __syncthreads();
  s  = red[0] + red[2] + red[4] + red[6];
  ss = red[1] + red[3] + red[5] + red[7];
  const float mean = s * (1.f / 1024.f);
  float var = (ss - s * mean) * (1.f / 1023.f);
  var = fmaxf(var, 0.f);
  const float k = al[0] / (sqrtf(var) + 1e-6f);
  const float g = be[0];
  ushort4 o;
  o.x = f2bf((v.x - mean) * k + g);
  o.y = f2bf((v.y - mean) * k + g);
  o.z = f2bf((v.z - mean) * k + g);
  o.w = f2bf((v.w - mean) * k + g);
  ((ushort4*)(out + (long)row * Dc))[tid] = o;
}

// ---------- GEMM: C[M][N] = A[M][K](bf16) * BT[N][K](bf16) + bias (+res)(relu) ----------
// 128x128 tile, BK=32, 4 waves (2x2), 16x16x32 bf16 MFMA, global_load_lds staging.
template<int RELU, int OUTBF16, int RES>
__global__ __launch_bounds__(256)
void gemm_bt(const unsigned short* __restrict__ A, const unsigned short* __restrict__ BT,
             const float* __restrict__ bias, const float* __restrict__ resid,
             void* __restrict__ Cout, int M, int N, int K){
  __shared__ unsigned short As[128 * 32];
  __shared__ unsigned short Bs[128 * 32];
  const int tid  = threadIdx.x;
  const int wid  = tid >> 6, lane = tid & 63;
  const int lg   = lane >> 4, lr = lane & 15;
  const int m0   = blockIdx.y * 128, n0 = blockIdx.x * 128;
  const int wr   = wid >> 1, wc = wid & 1;
  const long ldA = (long)K * 2;
  const f32x4 zero4 = {0.f, 0.f, 0.f, 0.f};
  f32x4 acc[4][4];
#pragma unroll
  for (int i = 0; i < 4; i++)
#pragma unroll
    for (int j = 0; j < 4; j++) acc[i][j] = zero4;

  for (int kt = 0; kt < K; kt += 32){
    __syncthreads();
#pragma unroll
    for (int ld = 0; ld < 2; ++ld){
      const int o  = (wid * 2 + ld) * 1024;          // 1024B per gload16 (64 lanes x 16B)
      const int ol = o + lane * 16;
      const int r  = ol >> 6, cb = ol & 63;          // row (64B per row), col-byte
      gload16((const char*)A  + (long)(m0 + r) * ldA + kt * 2 + cb, (char*)As + o);
      gload16((const char*)BT + (long)(n0 + r) * ldA + kt * 2 + cb, (char*)Bs + o);
    }
    __syncthreads();
    bf16x8 af[4], bfr[4];
#pragma unroll
    for (int mi = 0; mi < 4; mi++)
      af[mi] = *reinterpret_cast<const bf16x8*>(As + (wr*64 + mi*16 + lr) * 32 + lg * 8);
#pragma unroll
    for (int ni = 0; ni < 4; ni++)
      bfr[ni] = *reinterpret_cast<const bf16x8*>(Bs + (wc*64 + ni*16 + lr) * 32 + lg * 8);
#pragma unroll
    for (int mi = 0; mi < 4; mi++)
#pragma unroll
      for (int ni = 0; ni < 4; ni++)
        acc[mi][ni] = mfma16(af[mi], bfr[ni], acc[mi][ni]);
  }
#pragma unroll
  for (int mi = 0; mi < 4; mi++)
#pragma unroll
    for (int ni = 0; ni < 4; ni++){
      const int col = n0 + wc*64 + ni*16 + lr;
      const float bc = bias[col];
#pragma unroll
      for (int r = 0; r < 4; r++){
        const int row = m0 + wr*64 + mi*16 + lg*4 + r;
        float v = acc[mi][ni][r] + bc;
        if (RES)  v += resid[(long)row * N + col];
        if (RELU) v = fmaxf(v, 0.f);
        if (OUTBF16) ((unsigned short*)Cout)[(long)row * N + col] = f2bf(v);
        else         ((float*)Cout)[(long)row * N + col] = v;
      }
    }
}

// ---------- V transpose: qkv[.,2048+h*64+dk] -> vt[bh][dk][s] ----------
__global__ __launch_bounds__(256)
void transpose_v(const unsigned short* __restrict__ qkv, unsigned short* __restrict__ vt){
  __shared__ unsigned short tile[64][72];
  const int st = blockIdx.x * 64, bh = blockIdx.y;
  const int b = bh >> 4, h = bh & 15;
  const int tid = threadIdx.x;
  const int r = tid >> 2, c0 = (tid & 3) * 16;
  const unsigned short* src = qkv + ((long)(b*Sc + st + r) * 3072 + 2048 + h*64 + c0);
  *(uint4*)&tile[r][c0]     = *(const uint4*)src;
  *(uint4*)&tile[r][c0 + 8] = *(const uint4*)(src + 8);
  __syncthreads();
  union { unsigned short u[8]; uint4 v; } w0, w1;
#pragma unroll
  for (int j = 0; j < 8; j++){ w0.u[j] = tile[c0 + j][r]; w1.u[j] = tile[c0 + 8 + j][r]; }
  unsigned short* dst = vt + ((long)(bh*64 + r) * Sc + st + c0);
  *(uint4*)dst       = w0.v;
  *(uint4*)(dst + 8) = w1.v;
}

// ---------- flash attention, swapped QK^T (in-lane softmax) ----------
// Block: 4 waves, 64 q rows (wave w -> q rows s0+w*16..+15), KBLK=64.
// S^T = mfma(K, Q): lane (lr,lg) holds S[k = ni*16+lg*4+r][q = lr].
// Row softmax: in-lane over 16 values + shfl_xor(16,32) across lg.
// PV: A = P (from LDS round-trip), B = V^T tile -> O[q=lg*4+r][d=ni*16+lr].
__global__ __launch_bounds__(256)
void attn_k(const unsigned short* __restrict__ qkv, const unsigned short* __restrict__ vt,
            const int* __restrict__ mask, unsigned short* __restrict__ ctx){
  __shared__ unsigned short Qs[64*64], Ks[64*64], Vs[64*64], Ps[4*16*64];
  const int tid = threadIdx.x, wid = tid >> 6, lane = tid & 63;
  const int lg = lane >> 4, lr = lane & 15;
  const int qt = blockIdx.x, bh = blockIdx.y;
  const int b = bh >> 4, h = bh & 15;
  const int s0 = qt * 64;
  const f32x4 zero4 = {0.f, 0.f, 0.f, 0.f};

  // stage Q (swizzled source: 16B chunk c holds global chunk c^(r&7))
  const char* qbase = (const char*)qkv + ((long)(b*Sc + s0)) * 6144 + h * 128;
#pragma unroll
  for (int ld = 0; ld < 2; ++ld){
    const int o = (wid*2 + ld) * 1024;
    const int ol = o + lane * 16;
    const int r = ol >> 7, c = (ol >> 4) & 7;
    gload16(qbase + (long)r * 6144 + ((c ^ (r & 7)) << 4), (char*)Qs + o);
  }
  __syncthreads();
  // Q as B-operand: B[row = q_local = lr][d = ks*32 + lg*8 .. +7], hoisted out of k-loop
  bf16x8 qb[2];
#pragma unroll
  for (int ks = 0; ks < 2; ++ks){
    const int row = wid*16 + lr;
    const int c = ks*4 + lg;
    qb[ks] = *reinterpret_cast<const bf16x8*>((const char*)Qs + row*128 + ((c ^ (row & 7)) << 4));
  }

  float m_ = -1e30f, l_ = 0.f;
  f32x4 acc[4] = {zero4, zero4, zero4, zero4};

  const char* kbase = (const char*)qkv + (long)(b*Sc) * 6144 + 2048 + h * 128;
  const char* vbase = (const char*)vt + (long)bh * 64 * 4096;
  const int* mrow = mask + b * Sc;
  unsigned short* pb = Ps + wid * 1024;   // this wave's 16x64 P strip

  for (int t = 0; t < Sc / 64; ++t){
    const int k0 = t * 64;
    // mask for this lane's 16 k values: int4 at k0 + ni*16 + lg*4 (issue early)
    int4 mk[4];
#pragma unroll
    for (int ni = 0; ni < 4; ++ni) mk[ni] = *(const int4*)(mrow + k0 + ni*16 + lg*4);

    __syncthreads();   // prev-tile PV LDS reads complete
#pragma unroll
    for (int ld = 0; ld < 2; ++ld){
      const int o = (wid*2 + ld) * 1024;
      const int ol = o + lane * 16;
      const int r = ol >> 7, c = (ol >> 4) & 7;
      const int sw = ((c ^ (r & 7)) << 4);
      gload16(kbase + (long)(k0 + r) * 6144 + sw, (char*)Ks + o);
      gload16(vbase + (long)r * 4096 + k0 * 2 + sw, (char*)Vs + o);
    }
    __syncthreads();

    // S^T = K * Q^T : A-tile ni = k rows ni*16..+15
    f32x4 s4[4];
#pragma unroll
    for (int ni = 0; ni < 4; ++ni){
      s4[ni] = zero4;
      const int row = ni*16 + lr;
#pragma unroll
      for (int ks = 0; ks < 2; ++ks){
        const int c = ks*4 + lg;
        bf16x8 ak = *reinterpret_cast<const bf16x8*>((const char*)Ks + row*128 + ((c ^ (lr & 7)) << 4));
        s4[ni] = mfma16(ak, qb[ks], s4[ni]);
      }
    }
    // scale + mask (exact replace with -1e9 per reference)
    float p[4][4];
#pragma unroll
    for (int ni = 0; ni < 4; ++ni){
      p[ni][0] = (mk[ni].x != 0) ? s4[ni][0] * 0.125f : -1e9f;
      p[ni][1] = (mk[ni].y != 0) ? s4[ni][1] * 0.125f : -1e9f;
      p[ni][2] = (mk[ni].z != 0) ? s4[ni][2] * 0.125f : -1e9f;
      p[ni][3] = (mk[ni].w != 0) ? s4[ni][3] * 0.125f : -1e9f;
    }
    // row (q=lr) max: in-lane 16 + across lg
    float mx = fmaxf(fmaxf(p[0][0], p[0][1]), fmaxf(p[0][2], p[0][3]));
#pragma unroll
    for (int ni = 1; ni < 4; ++ni)
      mx = fmaxf(mx, fmaxf(fmaxf(p[ni][0], p[ni][1]), fmaxf(p[ni][2], p[ni][3])));
    mx = fmaxf(mx, __shfl_xor(mx, 16, 64));
    mx = fmaxf(mx, __shfl_xor(mx, 32, 64));
    const float mnew = fmaxf(m_, mx);
    const float scal = __expf(m_ - mnew);
    m_ = mnew;
    float rs = 0.f;
#pragma unroll
    for (int ni = 0; ni < 4; ++ni)
#pragma unroll
      for (int r = 0; r < 4; ++r){ p[ni][r] = __expf(p[ni][r] - mnew); rs += p[ni][r]; }
    rs += __shfl_xor(rs, 16, 64);
    rs += __shfl_xor(rs, 32, 64);
    l_ = l_ * scal + rs;
    // rescale acc (acc rows are q = lg*4+r; fetch their scal from lane lg*4+r)
    float sr[4];
#pragma unroll
    for (int r = 0; r < 4; ++r) sr[r] = __shfl(scal, lg*4 + r, 64);
#pragma unroll
    for (int ni = 0; ni < 4; ++ni)
#pragma unroll
      for (int r = 0; r < 4; ++r) acc[ni][r] *= sr[r];

    // pack P -> Ps [q=lr][k], 16B-chunk XOR swizzle by (lr&7); b64 writes
#pragma unroll
    for (int ni = 0; ni < 4; ++ni){
      uint32_t lo = (uint32_t)f2bf(p[ni][0]) | ((uint32_t)f2bf(p[ni][1]) << 16);
      uint32_t hi = (uint32_t)f2bf(p[ni][2]) | ((uint32_t)f2bf(p[ni][3]) << 16);
      const int c = ni*2 + (lg >> 1);
      char* dst = (char*)pb + lr*128 + ((c ^ (lr & 7)) << 4) + (lg & 1) * 8;
      uint2 w; w.x = lo; w.y = hi;
      *(uint2*)dst = w;
    }
    // read back as A-frags: P[q=lr][k = ks*32 + lg*8 .. +7]
    bf16x8 pa[2];
#pragma unroll
    for (int ks = 0; ks < 2; ++ks){
      const int c = ks*4 + lg;
      pa[ks] = *reinterpret_cast<const bf16x8*>((const char*)pb + lr*128 + ((c ^ (lr & 7)) << 4));
    }
    // PV: B = V^T rows d = ni*16+lr
#pragma unroll
    for (int ni = 0; ni < 4; ++ni){
      const int row = ni*16 + lr;
#pragma unroll
      for (int ks = 0; ks < 2; ++ks){
        const int c = ks*4 + lg;
        bf16x8 bv8 = *reinterpret_cast<const bf16x8*>((const char*)Vs + row*128 + ((c ^ (lr & 7)) << 4));
        acc[ni] = mfma16(pa[ks], bv8, acc[ni]);
      }
    }
  }
  // epilogue: O[q = lg*4+r][d = ni*16+lr] = acc/l(q)
  float lrw[4];
#pragma unroll
  for (int r = 0; r < 4; ++r) lrw[r] = __shfl(l_, lg*4 + r, 64);
#pragma unroll
  for (int ni = 0; ni < 4; ++ni){
    const int col = h*64 + ni*16 + lr;
#pragma unroll
    for (int r = 0; r < 4; ++r){
      const int row = s0 + wid*16 + lg*4 + r;
      ctx[(long)(b*Sc + row) * Dc + col] = f2bf(acc[ni][r] / lrw[r]);
    }
  }
}

// ---------- host ----------
extern "C" void kernel_launch(void* const* d_in, const int* in_sizes, int n_in,
                              void* d_out, int out_size, void* d_ws, size_t ws_size,
                              hipStream_t stream){
  const float* x  = (const float*)d_in[0];
  const int* mask = (const int*)d_in[1];
  const float* wq = (const float*)d_in[2];
  const float* bq = (const float*)d_in[3];
  const float* wk = (const float*)d_in[4];
  const float* bk = (const float*)d_in[5];
  const float* wv = (const float*)d_in[6];
  const float* bv = (const float*)d_in[7];
  const float* wo = (const float*)d_in[8];
  const float* bo = (const float*)d_in[9];
  const float* w1 = (const float*)d_in[10];
  const float* b1 = (const float*)d_in[11];
  const float* w2 = (const float*)d_in[12];
  const float* b2 = (const float*)d_in[13];
  const float* a1 = (const float*)d_in[14];
  const float* g1 = (const float*)d_in[15];
  const float* a2 = (const float*)d_in[16];
  const float* g2 = (const float*)d_in[17];

  if (ws_size < 75509760u) return;   // workspace layout below needs ~75.5 MB

  char* ws = (char*)d_ws;
  unsigned short* wqkv_t = (unsigned short*)(ws + 0);          // [3072][1024]
  unsigned short* wo_t   = (unsigned short*)(ws + 6291456);    // [1024][1024]
  unsigned short* w1_t   = (unsigned short*)(ws + 8388608);    // [4096][1024]
  unsigned short* w2_t   = (unsigned short*)(ws + 16777216);   // [1024][4096]
  float*          bqkv   = (float*)(ws + 25165824);            // [3072]
  unsigned short* nbuf   = (unsigned short*)(ws + 25178112);   // [4096][1024] (n1 then n2)
  unsigned short* qkv    = (unsigned short*)(ws + 33566720);   // [4096][3072]
  unsigned short* ff1    = (unsigned short*)(ws + 33566720);   // [4096][4096] (reuses qkv+vt)
  unsigned short* vt     = (unsigned short*)(ws + 58732544);   // [32][64][2048]
  unsigned short* ctx    = (unsigned short*)(ws + 67121152);   // [4096][1024]
  float* x2 = (float*)d_out;                                   // [4096][1024] f32

  const dim3 tb(32, 8);
  transpose_w<<<dim3(32, 32),  tb, 0, stream>>>(wq, wqkv_t,            1024, 1024);
  transpose_w<<<dim3(32, 32),  tb, 0, stream>>>(wk, wqkv_t + 1048576,  1024, 1024);
  transpose_w<<<dim3(32, 32),  tb, 0, stream>>>(wv, wqkv_t + 2097152,  1024, 1024);
  transpose_w<<<dim3(32, 32),  tb, 0, stream>>>(wo, wo_t,              1024, 1024);
  transpose_w<<<dim3(128, 32), tb, 0, stream>>>(w1, w1_t,              1024, 4096);
  transpose_w<<<dim3(32, 128), tb, 0, stream>>>(w2, w2_t,              4096, 1024);
  concat_bias<<<12, 256, 0, stream>>>(bq, bk, bv, bqkv);

  layernorm_k<<<BSc, 256, 0, stream>>>(x, a1, g1, nbuf);
  gemm_bt<0,1,0><<<dim3(24, 32), 256, 0, stream>>>(nbuf, wqkv_t, bqkv, nullptr, qkv, BSc, 3072, 1024);
  transpose_v<<<dim3(32, 32), 256, 0, stream>>>(qkv, vt);
  attn_k<<<dim3(32, 32), 256, 0, stream>>>(qkv, vt, mask, ctx);
  gemm_bt<0,0,1><<<dim3(8, 32), 256, 0, stream>>>(ctx, wo_t, bo, x, x2, BSc, 1024, 1024);
  layernorm_k<<<BSc, 256, 0, stream>>>(x2, a2, g2, nbuf);
  gemm_bt<1,1,0><<<dim3(32, 32), 256, 0, stream>>>(nbuf, w1_t, b1, nullptr, ff1, BSc, 4096, 1024);
  gemm_bt<0,0,1><<<dim3(8, 32), 256, 0, stream>>>(ff1, w2_t, b2, x2, d_out, BSc, 1024, 4096);
}

// Round 4
// 333.907 us; speedup vs baseline: 1.1151x; 1.0373x over previous
//
#include <hip/hip_runtime.h>
#include <hip/hip_bf16.h>
#include <cstdint>

// ---------- problem constants ----------
constexpr int Bc  = 2;
constexpr int Sc  = 2048;
constexpr int Dc  = 1024;
constexpr int Hc  = 16;
constexpr int DKc = 64;
constexpr int DFFc= 4096;
constexpr int BSc = Bc * Sc;      // 4096 rows

typedef __attribute__((ext_vector_type(8))) short bf16x8;
typedef __attribute__((ext_vector_type(4))) float f32x4;

__device__ __forceinline__ unsigned short f2bf(float x){
  union { float f; uint32_t u; } v; v.f = x;
  uint32_t r = v.u + 0x7fffu + ((v.u >> 16) & 1u);   // RNE
  return (unsigned short)(r >> 16);
}

__device__ __forceinline__ void gload16(const void* g, void* l){
  __builtin_amdgcn_global_load_lds((const __attribute__((address_space(1))) void*)g,
                                   (__attribute__((address_space(3))) void*)l, 16, 0, 0);
}

__device__ __forceinline__ f32x4 mfma16(bf16x8 a, bf16x8 b, f32x4 c){
  return __builtin_amdgcn_mfma_f32_16x16x32_bf16(a, b, c, 0, 0, 0);
}

// pack two f32 -> one u32 of 2x bf16 (v_cvt_pk_bf16_f32)
__device__ __forceinline__ uint32_t pk2bf(float lo, float hi){
  __hip_bfloat162 h = __float22bfloat162_rn(make_float2(lo, hi));
  return *reinterpret_cast<uint32_t*>(&h);
}

// ---------- weight transpose f32[K][N] -> bf16[N][K] ----------
__global__ __launch_bounds__(256)
void transpose_w(const float* __restrict__ in, unsigned short* __restrict__ out,
                 int K, int N){
  __shared__ float t[32][33];
  const int tx = threadIdx.x, ty = threadIdx.y;
  const int x0 = blockIdx.x * 32, y0 = blockIdx.y * 32;
#pragma unroll
  for (int j = ty; j < 32; j += 8) t[j][tx] = in[(long)(y0 + j) * N + x0 + tx];
  __syncthreads();
#pragma unroll
  for (int j = ty; j < 32; j += 8)
    out[(long)(x0 + j) * K + y0 + tx] = f2bf(t[tx][j]);
}

__global__ __launch_bounds__(256)
void concat_bias(const float* __restrict__ bq, const float* __restrict__ bk,
                 const float* __restrict__ bv, float* __restrict__ bqkv){
  int i = blockIdx.x * 256 + threadIdx.x;   // 0..3071
  float v = (i < 1024) ? bq[i] : (i < 2048 ? bk[i - 1024] : bv[i - 2048]);
  bqkv[i] = v;
}

// ---------- layernorm (ddof=1, eps on std, scalar alpha/beta) f32 -> bf16 ----------
__global__ __launch_bounds__(256)
void layernorm_k(const float* __restrict__ x, const float* __restrict__ al,
                 const float* __restrict__ be, unsigned short* __restrict__ out){
  const int row = blockIdx.x, tid = threadIdx.x;
  const float4 v = ((const float4*)(x + (long)row * Dc))[tid];
  float s  = v.x + v.y + v.z + v.w;
  float ss = v.x*v.x + v.y*v.y + v.z*v.z + v.w*v.w;
#pragma unroll
  for (int d = 1; d < 64; d <<= 1){ s += __shfl_xor(s, d, 64); ss += __shfl_xor(ss, d, 64); }
  __shared__ float red[8];
  const int wid = tid >> 6, lane = tid & 63;
  if (lane == 0){ red[wid*2] = s; red[wid*2+1] = ss; }
  __syncthreads();
  s  = red[0] + red[2] + red[4] + red[6];
  ss = red[1] + red[3] + red[5] + red[7];
  const float mean = s * (1.f / 1024.f);
  float var = (ss - s * mean) * (1.f / 1023.f);
  var = fmaxf(var, 0.f);
  const float k = al[0] / (sqrtf(var) + 1e-6f);
  const float g = be[0];
  ushort4 o;
  o.x = f2bf((v.x - mean) * k + g);
  o.y = f2bf((v.y - mean) * k + g);
  o.z = f2bf((v.z - mean) * k + g);
  o.w = f2bf((v.w - mean) * k + g);
  ((ushort4*)(out + (long)row * Dc))[tid] = o;
}

// ---------- GEMM: C[M][N] = A[M][K](bf16) * BT[N][K](bf16) + bias (+res)(relu) ----------
// 128x128 tile, BK=32, 4 waves (2x2), 16x16x32 bf16 MFMA, global_load_lds staging.
template<int RELU, int OUTBF16, int RES>
__global__ __launch_bounds__(256)
void gemm_bt(const unsigned short* __restrict__ A, const unsigned short* __restrict__ BT,
             const float* __restrict__ bias, const float* __restrict__ resid,
             void* __restrict__ Cout, int M, int N, int K){
  __shared__ unsigned short As[128 * 32];
  __shared__ unsigned short Bs[128 * 32];
  const int tid  = threadIdx.x;
  const int wid  = tid >> 6, lane = tid & 63;
  const int lg   = lane >> 4, lr = lane & 15;
  const int m0   = blockIdx.y * 128, n0 = blockIdx.x * 128;
  const int wr   = wid >> 1, wc = wid & 1;
  const long ldA = (long)K * 2;
  const f32x4 zero4 = {0.f, 0.f, 0.f, 0.f};
  f32x4 acc[4][4];
#pragma unroll
  for (int i = 0; i < 4; i++)
#pragma unroll
    for (int j = 0; j < 4; j++) acc[i][j] = zero4;

  for (int kt = 0; kt < K; kt += 32){
    __syncthreads();
#pragma unroll
    for (int ld = 0; ld < 2; ++ld){
      const int o  = (wid * 2 + ld) * 1024;          // 1024B per gload16 (64 lanes x 16B)
      const int ol = o + lane * 16;
      const int r  = ol >> 6, cb = ol & 63;          // row (64B per row), col-byte
      gload16((const char*)A  + (long)(m0 + r) * ldA + kt * 2 + cb, (char*)As + o);
      gload16((const char*)BT + (long)(n0 + r) * ldA + kt * 2 + cb, (char*)Bs + o);
    }
    __syncthreads();
    bf16x8 af[4], bfr[4];
#pragma unroll
    for (int mi = 0; mi < 4; mi++)
      af[mi] = *reinterpret_cast<const bf16x8*>(As + (wr*64 + mi*16 + lr) * 32 + lg * 8);
#pragma unroll
    for (int ni = 0; ni < 4; ni++)
      bfr[ni] = *reinterpret_cast<const bf16x8*>(Bs + (wc*64 + ni*16 + lr) * 32 + lg * 8);
#pragma unroll
    for (int mi = 0; mi < 4; mi++)
#pragma unroll
      for (int ni = 0; ni < 4; ni++)
        acc[mi][ni] = mfma16(af[mi], bfr[ni], acc[mi][ni]);
  }
#pragma unroll
  for (int mi = 0; mi < 4; mi++)
#pragma unroll
    for (int ni = 0; ni < 4; ni++){
      const int col = n0 + wc*64 + ni*16 + lr;
      const float bc = bias[col];
#pragma unroll
      for (int r = 0; r < 4; r++){
        const int row = m0 + wr*64 + mi*16 + lg*4 + r;
        float v = acc[mi][ni][r] + bc;
        if (RES)  v += resid[(long)row * N + col];
        if (RELU) v = fmaxf(v, 0.f);
        if (OUTBF16) ((unsigned short*)Cout)[(long)row * N + col] = f2bf(v);
        else         ((float*)Cout)[(long)row * N + col] = v;
      }
    }
}

// ---------- V transpose: qkv[.,2048+h*64+dk] -> vt[bh][dk][s] ----------
__global__ __launch_bounds__(256)
void transpose_v(const unsigned short* __restrict__ qkv, unsigned short* __restrict__ vt){
  __shared__ unsigned short tile[64][72];
  const int st = blockIdx.x * 64, bh = blockIdx.y;
  const int b = bh >> 4, h = bh & 15;
  const int tid = threadIdx.x;
  const int r = tid >> 2, c0 = (tid & 3) * 16;
  const unsigned short* src = qkv + ((long)(b*Sc + st + r) * 3072 + 2048 + h*64 + c0);
  *(uint4*)&tile[r][c0]     = *(const uint4*)src;
  *(uint4*)&tile[r][c0 + 8] = *(const uint4*)(src + 8);
  __syncthreads();
  union { unsigned short u[8]; uint4 v; } w0, w1;
#pragma unroll
  for (int j = 0; j < 8; j++){ w0.u[j] = tile[c0 + j][r]; w1.u[j] = tile[c0 + 8 + j][r]; }
  unsigned short* dst = vt + ((long)(bh*64 + r) * Sc + st + c0);
  *(uint4*)dst       = w0.v;
  *(uint4*)(dst + 8) = w1.v;
}

// ---------- flash attention, swapped QK^T, in-lane softmax, l via ones-MFMA ----------
// Block: 4 waves, 64 q rows (wave w -> q rows s0+w*16..+15), KBLK=64.
// S^T = mfma(K, Q): lane (lr,lg) holds S[k = ni*16+lg*4+r][q = lr].
// Row softmax: in-lane over 16 values + shfl_xor(16,32) across lg; defer-max THR=8.
// PV: A = P (LDS round-trip), B = V^T tile -> O[q=lg*4+r][d=ni*16+lr].
// l accumulated as accS = mfma(P, ones) -> accS[r] = rowsum(q=lg*4+r), same index as acc.
__global__ __launch_bounds__(256)
void attn_k(const unsigned short* __restrict__ qkv, const unsigned short* __restrict__ vt,
            const int* __restrict__ mask, unsigned short* __restrict__ ctx){
  __shared__ unsigned short Qs[64*64], Ks[64*64], Vs[64*64], Ps[4*16*64];
  const int tid = threadIdx.x, wid = tid >> 6, lane = tid & 63;
  const int lg = lane >> 4, lr = lane & 15;
  const int qt = blockIdx.x, bh = blockIdx.y;
  const int b = bh >> 4, h = bh & 15;
  const int s0 = qt * 64;
  const f32x4 zero4 = {0.f, 0.f, 0.f, 0.f};
  const short onebf = (short)0x3F80;
  const bf16x8 ones = {onebf, onebf, onebf, onebf, onebf, onebf, onebf, onebf};

  // stage Q (swizzled source: 16B chunk c holds global chunk c^(r&7))
  const char* qbase = (const char*)qkv + ((long)(b*Sc + s0)) * 6144 + h * 128;
#pragma unroll
  for (int ld = 0; ld < 2; ++ld){
    const int o = (wid*2 + ld) * 1024;
    const int ol = o + lane * 16;
    const int r = ol >> 7, c = (ol >> 4) & 7;
    gload16(qbase + (long)r * 6144 + ((c ^ (r & 7)) << 4), (char*)Qs + o);
  }
  __syncthreads();
  // Q as B-operand: B[row = q_local = lr][d = ks*32 + lg*8 .. +7], hoisted out of k-loop
  bf16x8 qb[2];
#pragma unroll
  for (int ks = 0; ks < 2; ++ks){
    const int row = wid*16 + lr;
    const int c = ks*4 + lg;
    qb[ks] = *reinterpret_cast<const bf16x8*>((const char*)Qs + row*128 + ((c ^ (row & 7)) << 4));
  }

  float m_ = -1e30f;
  f32x4 acc[4] = {zero4, zero4, zero4, zero4};
  f32x4 accS = zero4;

  const char* kbase = (const char*)qkv + (long)(b*Sc) * 6144 + 2048 + h * 128;
  const char* vbase = (const char*)vt + (long)bh * 64 * 4096;
  const int* mrow = mask + b * Sc;
  unsigned short* pb = Ps + wid * 1024;   // this wave's 16x64 P strip

  for (int t = 0; t < Sc / 64; ++t){
    const int k0 = t * 64;
    // mask for this lane's 16 k values: int4 at k0 + ni*16 + lg*4 (issue early)
    int4 mk[4];
#pragma unroll
    for (int ni = 0; ni < 4; ++ni) mk[ni] = *(const int4*)(mrow + k0 + ni*16 + lg*4);

    __syncthreads();   // prev-tile PV LDS reads complete
#pragma unroll
    for (int ld = 0; ld < 2; ++ld){
      const int o = (wid*2 + ld) * 1024;
      const int ol = o + lane * 16;
      const int r = ol >> 7, c = (ol >> 4) & 7;
      const int sw = ((c ^ (r & 7)) << 4);
      gload16(kbase + (long)(k0 + r) * 6144 + sw, (char*)Ks + o);
      gload16(vbase + (long)r * 4096 + k0 * 2 + sw, (char*)Vs + o);
    }
    __syncthreads();

    // S^T = K * Q^T : A-tile ni = k rows ni*16..+15
    f32x4 s4[4];
#pragma unroll
    for (int ni = 0; ni < 4; ++ni){
      s4[ni] = zero4;
      const int row = ni*16 + lr;
#pragma unroll
      for (int ks = 0; ks < 2; ++ks){
        const int c = ks*4 + lg;
        bf16x8 ak = *reinterpret_cast<const bf16x8*>((const char*)Ks + row*128 + ((c ^ (lr & 7)) << 4));
        s4[ni] = mfma16(ak, qb[ks], s4[ni]);
      }
    }
    // scale + mask (exact replace with -1e9 per reference)
    float p[4][4];
#pragma unroll
    for (int ni = 0; ni < 4; ++ni)
#pragma unroll
      for (int r = 0; r < 4; ++r)
        p[ni][r] = ((&mk[ni].x)[r] != 0) ? s4[ni][r] * 0.125f : -1e9f;

    // row (q=lr) max: in-lane 16 + across lg
    float mx = fmaxf(fmaxf(p[0][0], p[0][1]), fmaxf(p[0][2], p[0][3]));
#pragma unroll
    for (int ni = 1; ni < 4; ++ni)
      mx = fmaxf(mx, fmaxf(fmaxf(p[ni][0], p[ni][1]), fmaxf(p[ni][2], p[ni][3])));
    mx = fmaxf(mx, __shfl_xor(mx, 16, 64));
    mx = fmaxf(mx, __shfl_xor(mx, 32, 64));

    // defer-max: only update m_/rescale when some row grew past THR=8 (wave-uniform branch)
    if (!__all(mx <= m_ + 8.f)){
      const float mnew = fmaxf(m_, mx);
      const float scal = __expf(m_ - mnew);
      m_ = mnew;
      float sr[4];
#pragma unroll
      for (int r = 0; r < 4; ++r) sr[r] = __shfl(scal, lg*4 + r, 64);
#pragma unroll
      for (int ni = 0; ni < 4; ++ni)
#pragma unroll
        for (int r = 0; r < 4; ++r) acc[ni][r] *= sr[r];
#pragma unroll
      for (int r = 0; r < 4; ++r) accS[r] *= sr[r];
    }

#pragma unroll
    for (int ni = 0; ni < 4; ++ni)
#pragma unroll
      for (int r = 0; r < 4; ++r) p[ni][r] = __expf(p[ni][r] - m_);

    // pack P -> Ps [q=lr][k] via v_cvt_pk_bf16_f32; 16B-chunk XOR swizzle by (lr&7); b64 writes
#pragma unroll
    for (int ni = 0; ni < 4; ++ni){
      uint2 w;
      w.x = pk2bf(p[ni][0], p[ni][1]);
      w.y = pk2bf(p[ni][2], p[ni][3]);
      const int c = ni*2 + (lg >> 1);
      char* dst = (char*)pb + lr*128 + ((c ^ (lr & 7)) << 4) + (lg & 1) * 8;
      *(uint2*)dst = w;
    }
    // read back as A-frags: P[q=lr][k = ks*32 + lg*8 .. +7]
    bf16x8 pa[2];
#pragma unroll
    for (int ks = 0; ks < 2; ++ks){
      const int c = ks*4 + lg;
      pa[ks] = *reinterpret_cast<const bf16x8*>((const char*)pb + lr*128 + ((c ^ (lr & 7)) << 4));
    }
    // l-accumulator: accS += P * ones
#pragma unroll
    for (int ks = 0; ks < 2; ++ks) accS = mfma16(pa[ks], ones, accS);
    // PV: B = V^T rows d = ni*16+lr
#pragma unroll
    for (int ni = 0; ni < 4; ++ni){
      const int row = ni*16 + lr;
#pragma unroll
      for (int ks = 0; ks < 2; ++ks){
        const int c = ks*4 + lg;
        bf16x8 bv8 = *reinterpret_cast<const bf16x8*>((const char*)Vs + row*128 + ((c ^ (lr & 7)) << 4));
        acc[ni] = mfma16(pa[ks], bv8, acc[ni]);
      }
    }
  }
  // epilogue: O[q = lg*4+r][d = ni*16+lr] = acc/accS  (accS[r] = l for q=lg*4+r)
#pragma unroll
  for (int ni = 0; ni < 4; ++ni){
    const int col = h*64 + ni*16 + lr;
#pragma unroll
    for (int r = 0; r < 4; ++r){
      const int row = s0 + wid*16 + lg*4 + r;
      ctx[(long)(b*Sc + row) * Dc + col] = f2bf(acc[ni][r] / accS[r]);
    }
  }
}

// ---------- host ----------
extern "C" void kernel_launch(void* const* d_in, const int* in_sizes, int n_in,
                              void* d_out, int out_size, void* d_ws, size_t ws_size,
                              hipStream_t stream){
  const float* x  = (const float*)d_in[0];
  const int* mask = (const int*)d_in[1];
  const float* wq = (const float*)d_in[2];
  const float* bq = (const float*)d_in[3];
  const float* wk = (const float*)d_in[4];
  const float* bk = (const float*)d_in[5];
  const float* wv = (const float*)d_in[6];
  const float* bv = (const float*)d_in[7];
  const float* wo = (const float*)d_in[8];
  const float* bo = (const float*)d_in[9];
  const float* w1 = (const float*)d_in[10];
  const float* b1 = (const float*)d_in[11];
  const float* w2 = (const float*)d_in[12];
  const float* b2 = (const float*)d_in[13];
  const float* a1 = (const float*)d_in[14];
  const float* g1 = (const float*)d_in[15];
  const float* a2 = (const float*)d_in[16];
  const float* g2 = (const float*)d_in[17];

  if (ws_size < 75509760u) return;   // workspace layout below needs ~75.5 MB

  char* ws = (char*)d_ws;
  unsigned short* wqkv_t = (unsigned short*)(ws + 0);          // [3072][1024]
  unsigned short* wo_t   = (unsigned short*)(ws + 6291456);    // [1024][1024]
  unsigned short* w1_t   = (unsigned short*)(ws + 8388608);    // [4096][1024]
  unsigned short* w2_t   = (unsigned short*)(ws + 16777216);   // [1024][4096]
  float*          bqkv   = (float*)(ws + 25165824);            // [3072]
  unsigned short* nbuf   = (unsigned short*)(ws + 25178112);   // [4096][1024] (n1 then n2)
  unsigned short* qkv    = (unsigned short*)(ws + 33566720);   // [4096][3072]
  unsigned short* ff1    = (unsigned short*)(ws + 33566720);   // [4096][4096] (reuses qkv+vt)
  unsigned short* vt     = (unsigned short*)(ws + 58732544);   // [32][64][2048]
  unsigned short* ctx    = (unsigned short*)(ws + 67121152);   // [4096][1024]
  float* x2 = (float*)d_out;                                   // [4096][1024] f32

  const dim3 tb(32, 8);
  transpose_w<<<dim3(32, 32),  tb, 0, stream>>>(wq, wqkv_t,            1024, 1024);
  transpose_w<<<dim3(32, 32),  tb, 0, stream>>>(wk, wqkv_t + 1048576,  1024, 1024);
  transpose_w<<<dim3(32, 32),  tb, 0, stream>>>(wv, wqkv_t + 2097152,  1024, 1024);
  transpose_w<<<dim3(32, 32),  tb, 0, stream>>>(wo, wo_t,              1024, 1024);
  transpose_w<<<dim3(128, 32), tb, 0, stream>>>(w1, w1_t,              1024, 4096);
  transpose_w<<<dim3(32, 128), tb, 0, stream>>>(w2, w2_t,              4096, 1024);
  concat_bias<<<12, 256, 0, stream>>>(bq, bk, bv, bqkv);

  layernorm_k<<<BSc, 256, 0, stream>>>(x, a1, g1, nbuf);
  gemm_bt<0,1,0><<<dim3(24, 32), 256, 0, stream>>>(nbuf, wqkv_t, bqkv, nullptr, qkv, BSc, 3072, 1024);
  transpose_v<<<dim3(32, 32), 256, 0, stream>>>(qkv, vt);
  attn_k<<<dim3(32, 32), 256, 0, stream>>>(qkv, vt, mask, ctx);
  gemm_bt<0,0,1><<<dim3(8, 32), 256, 0, stream>>>(ctx, wo_t, bo, x, x2, BSc, 1024, 1024);
  layernorm_k<<<BSc, 256, 0, stream>>>(x2, a2, g2, nbuf);
  gemm_bt<1,1,0><<<dim3(32, 32), 256, 0, stream>>>(nbuf, w1_t, b1, nullptr, ff1, BSc, 4096, 1024);
  gemm_bt<0,0,1><<<dim3(8, 32), 256, 0, stream>>>(ff1, w2_t, b2, x2, d_out, BSc, 1024, 4096);
}

// Round 5
// 283.944 us; speedup vs baseline: 1.3114x; 1.1760x over previous
//
#include <hip/hip_runtime.h>
#include <hip/hip_bf16.h>
#include <cstdint>

// ---------- problem constants ----------
constexpr int Bc  = 2;
constexpr int Sc  = 2048;
constexpr int Dc  = 1024;
constexpr int Hc  = 16;
constexpr int DKc = 64;
constexpr int DFFc= 4096;
constexpr int BSc = Bc * Sc;      // 4096 rows

typedef __attribute__((ext_vector_type(8))) short bf16x8;
typedef __attribute__((ext_vector_type(4))) float f32x4;

__device__ __forceinline__ unsigned short f2bf(float x){
  union { float f; uint32_t u; } v; v.f = x;
  uint32_t r = v.u + 0x7fffu + ((v.u >> 16) & 1u);   // RNE
  return (unsigned short)(r >> 16);
}

__device__ __forceinline__ void gload16(const void* g, void* l){
  __builtin_amdgcn_global_load_lds((const __attribute__((address_space(1))) void*)g,
                                   (__attribute__((address_space(3))) void*)l, 16, 0, 0);
}

__device__ __forceinline__ f32x4 mfma16(bf16x8 a, bf16x8 b, f32x4 c){
  return __builtin_amdgcn_mfma_f32_16x16x32_bf16(a, b, c, 0, 0, 0);
}

// pack two f32 -> one u32 of 2x bf16 (v_cvt_pk_bf16_f32)
__device__ __forceinline__ uint32_t pk2bf(float lo, float hi){
  __hip_bfloat162 h = __float22bfloat162_rn(make_float2(lo, hi));
  return *reinterpret_cast<uint32_t*>(&h);
}

// bijective XCD swizzle (T1, m204 form)
__device__ __forceinline__ int xcd_swz(int bid, int nwg){
  const int q = nwg >> 3, r = nwg & 7;
  const int xcd = bid & 7, idx = bid >> 3;
  return ((xcd < r) ? (xcd * (q + 1)) : (r * (q + 1) + (xcd - r) * q)) + idx;
}

// ---------- weight transpose f32[K][N] -> bf16[N][K] ----------
__global__ __launch_bounds__(256)
void transpose_w(const float* __restrict__ in, unsigned short* __restrict__ out,
                 int K, int N){
  __shared__ float t[32][33];
  const int tx = threadIdx.x, ty = threadIdx.y;
  const int x0 = blockIdx.x * 32, y0 = blockIdx.y * 32;
#pragma unroll
  for (int j = ty; j < 32; j += 8) t[j][tx] = in[(long)(y0 + j) * N + x0 + tx];
  __syncthreads();
#pragma unroll
  for (int j = ty; j < 32; j += 8)
    out[(long)(x0 + j) * K + y0 + tx] = f2bf(t[tx][j]);
}

__global__ __launch_bounds__(256)
void concat_bias(const float* __restrict__ bq, const float* __restrict__ bk,
                 const float* __restrict__ bv, float* __restrict__ bqkv){
  int i = blockIdx.x * 256 + threadIdx.x;   // 0..3071
  float v = (i < 1024) ? bq[i] : (i < 2048 ? bk[i - 1024] : bv[i - 2048]);
  bqkv[i] = v;
}

// ---------- layernorm (ddof=1, eps on std, scalar alpha/beta) f32 -> bf16 ----------
__global__ __launch_bounds__(256)
void layernorm_k(const float* __restrict__ x, const float* __restrict__ al,
                 const float* __restrict__ be, unsigned short* __restrict__ out){
  const int row = blockIdx.x, tid = threadIdx.x;
  const float4 v = ((const float4*)(x + (long)row * Dc))[tid];
  float s  = v.x + v.y + v.z + v.w;
  float ss = v.x*v.x + v.y*v.y + v.z*v.z + v.w*v.w;
#pragma unroll
  for (int d = 1; d < 64; d <<= 1){ s += __shfl_xor(s, d, 64); ss += __shfl_xor(ss, d, 64); }
  __shared__ float red[8];
  const int wid = tid >> 6, lane = tid & 63;
  if (lane == 0){ red[wid*2] = s; red[wid*2+1] = ss; }
  __syncthreads();
  s  = red[0] + red[2] + red[4] + red[6];
  ss = red[1] + red[3] + red[5] + red[7];
  const float mean = s * (1.f / 1024.f);
  float var = (ss - s * mean) * (1.f / 1023.f);
  var = fmaxf(var, 0.f);
  const float k = al[0] / (sqrtf(var) + 1e-6f);
  const float g = be[0];
  ushort4 o;
  o.x = f2bf((v.x - mean) * k + g);
  o.y = f2bf((v.y - mean) * k + g);
  o.z = f2bf((v.z - mean) * k + g);
  o.w = f2bf((v.w - mean) * k + g);
  ((ushort4*)(out + (long)row * Dc))[tid] = o;
}

// ============ 256x256 GEMM, BK=64, 8 waves (2Mx4N), 2-phase dbuf ============
// LDS: 2 x (A 256x64 + B 256x64) bf16 = 128 KiB. Staged via global_load_lds
// with pre-swizzled source (16B chunk c holds global chunk c^(row&7)); reads
// apply the same XOR -> ~2-way conflicts instead of 16-way.
template<int RELU, int OUTBF16, int RES>
__global__ __launch_bounds__(512, 2)
void gemm256(const unsigned short* __restrict__ A, const unsigned short* __restrict__ BT,
             const float* __restrict__ bias, const float* __restrict__ resid,
             void* __restrict__ Cout, int M, int N, int K){
  __shared__ unsigned short As[2][256 * 64];
  __shared__ unsigned short Bs[2][256 * 64];
  const int tid = threadIdx.x, wid = tid >> 6, lane = tid & 63;
  const int lg = lane >> 4, lr = lane & 15;
  const int wm = wid >> 2, wn = wid & 3;
  const int nwg = gridDim.x * gridDim.y;
  const int wg  = xcd_swz(blockIdx.y * gridDim.x + blockIdx.x, nwg);
  const int bx = wg % gridDim.x, by = wg / gridDim.x;
  const int m0 = by * 256, n0 = bx * 256;
  const long ldA = (long)K * 2;
  const f32x4 zero4 = {0.f, 0.f, 0.f, 0.f};
  f32x4 acc[8][4];
#pragma unroll
  for (int i = 0; i < 8; i++)
#pragma unroll
    for (int j = 0; j < 4; j++) acc[i][j] = zero4;

  const int obase0 = wid * 64 * 16;     // wave-uniform LDS byte base for l=0

  // stage k-tile kt into buffer b
  auto stage = [&](int b, int kt){
#pragma unroll
    for (int l = 0; l < 4; ++l){
      const int ob = l * 8192 + obase0;          // wave-uniform
      const int o  = ob + lane * 16;
      const int rr = o >> 7, c = (o >> 4) & 7;
      const long co = (long)kt * 128 + ((c ^ (rr & 7)) << 4);
      gload16((const char*)A  + (long)(m0 + rr) * ldA + co, (char*)As[b] + ob);
      gload16((const char*)BT + (long)(n0 + rr) * ldA + co, (char*)Bs[b] + ob);
    }
  };

  const int nt = K >> 6;
  stage(0, 0);
  __syncthreads();

  int cur = 0;
  for (int t = 0; t < nt; ++t){
    if (t + 1 < nt) stage(cur ^ 1, t + 1);
    const char* as = (const char*)As[cur];
    const char* bs = (const char*)Bs[cur];
    bf16x8 bfr[4][2];
#pragma unroll
    for (int ni = 0; ni < 4; ++ni){
      const int row = wn*64 + ni*16 + lr;
#pragma unroll
      for (int ks = 0; ks < 2; ++ks)
        bfr[ni][ks] = *reinterpret_cast<const bf16x8*>(bs + row*128 + (((ks*4 + lg) ^ (row & 7)) << 4));
    }
    __builtin_amdgcn_s_setprio(1);
#pragma unroll
    for (int mi = 0; mi < 8; ++mi){
      const int arow = wm*128 + mi*16 + lr;
      bf16x8 a0 = *reinterpret_cast<const bf16x8*>(as + arow*128 + (((0*4 + lg) ^ (arow & 7)) << 4));
      bf16x8 a1 = *reinterpret_cast<const bf16x8*>(as + arow*128 + (((1*4 + lg) ^ (arow & 7)) << 4));
#pragma unroll
      for (int ni = 0; ni < 4; ++ni){
        acc[mi][ni] = mfma16(a0, bfr[ni][0], acc[mi][ni]);
        acc[mi][ni] = mfma16(a1, bfr[ni][1], acc[mi][ni]);
      }
    }
    __builtin_amdgcn_s_setprio(0);
    __syncthreads();     // drains vmcnt(0)+lgkmcnt(0): prefetch landed, reads done
    cur ^= 1;
  }

#pragma unroll
  for (int mi = 0; mi < 8; ++mi)
#pragma unroll
    for (int ni = 0; ni < 4; ++ni){
      const int col = n0 + wn*64 + ni*16 + lr;
      const float bc = bias[col];
#pragma unroll
      for (int r = 0; r < 4; ++r){
        const int row = m0 + wm*128 + mi*16 + lg*4 + r;
        float v = acc[mi][ni][r] + bc;
        if (RES)  v += resid[(long)row * N + col];
        if (RELU) v = fmaxf(v, 0.f);
        if (OUTBF16) ((unsigned short*)Cout)[(long)row * N + col] = f2bf(v);
        else         ((float*)Cout)[(long)row * N + col] = v;
      }
    }
}

// ============ 128x128 GEMM, BK=64, 4 waves (2x2), 2-phase dbuf ============
// LDS: 2 x (A 128x64 + B 128x64) bf16 = 64 KiB (2 blocks/CU).
template<int RELU, int OUTBF16, int RES>
__global__ __launch_bounds__(256, 2)
void gemm128(const unsigned short* __restrict__ A, const unsigned short* __restrict__ BT,
             const float* __restrict__ bias, const float* __restrict__ resid,
             void* __restrict__ Cout, int M, int N, int K){
  __shared__ unsigned short As[2][128 * 64];
  __shared__ unsigned short Bs[2][128 * 64];
  const int tid = threadIdx.x, wid = tid >> 6, lane = tid & 63;
  const int lg = lane >> 4, lr = lane & 15;
  const int wm = wid >> 1, wn = wid & 1;
  const int nwg = gridDim.x * gridDim.y;
  const int wg  = xcd_swz(blockIdx.y * gridDim.x + blockIdx.x, nwg);
  const int bx = wg % gridDim.x, by = wg / gridDim.x;
  const int m0 = by * 128, n0 = bx * 128;
  const long ldA = (long)K * 2;
  const f32x4 zero4 = {0.f, 0.f, 0.f, 0.f};
  f32x4 acc[4][4];
#pragma unroll
  for (int i = 0; i < 4; i++)
#pragma unroll
    for (int j = 0; j < 4; j++) acc[i][j] = zero4;

  const int obase0 = wid * 64 * 16;

  auto stage = [&](int b, int kt){
#pragma unroll
    for (int l = 0; l < 4; ++l){
      const int ob = l * 4096 + obase0;
      const int o  = ob + lane * 16;
      const int rr = o >> 7, c = (o >> 4) & 7;
      const long co = (long)kt * 128 + ((c ^ (rr & 7)) << 4);
      gload16((const char*)A  + (long)(m0 + rr) * ldA + co, (char*)As[b] + ob);
      gload16((const char*)BT + (long)(n0 + rr) * ldA + co, (char*)Bs[b] + ob);
    }
  };

  const int nt = K >> 6;
  stage(0, 0);
  __syncthreads();

  int cur = 0;
  for (int t = 0; t < nt; ++t){
    if (t + 1 < nt) stage(cur ^ 1, t + 1);
    const char* as = (const char*)As[cur];
    const char* bs = (const char*)Bs[cur];
    bf16x8 bfr[4][2];
#pragma unroll
    for (int ni = 0; ni < 4; ++ni){
      const int row = wn*64 + ni*16 + lr;
#pragma unroll
      for (int ks = 0; ks < 2; ++ks)
        bfr[ni][ks] = *reinterpret_cast<const bf16x8*>(bs + row*128 + (((ks*4 + lg) ^ (row & 7)) << 4));
    }
    __builtin_amdgcn_s_setprio(1);
#pragma unroll
    for (int mi = 0; mi < 4; ++mi){
      const int arow = wm*64 + mi*16 + lr;
      bf16x8 a0 = *reinterpret_cast<const bf16x8*>(as + arow*128 + (((0*4 + lg) ^ (arow & 7)) << 4));
      bf16x8 a1 = *reinterpret_cast<const bf16x8*>(as + arow*128 + (((1*4 + lg) ^ (arow & 7)) << 4));
#pragma unroll
      for (int ni = 0; ni < 4; ++ni){
        acc[mi][ni] = mfma16(a0, bfr[ni][0], acc[mi][ni]);
        acc[mi][ni] = mfma16(a1, bfr[ni][1], acc[mi][ni]);
      }
    }
    __builtin_amdgcn_s_setprio(0);
    __syncthreads();
    cur ^= 1;
  }

#pragma unroll
  for (int mi = 0; mi < 4; ++mi)
#pragma unroll
    for (int ni = 0; ni < 4; ++ni){
      const int col = n0 + wn*64 + ni*16 + lr;
      const float bc = bias[col];
#pragma unroll
      for (int r = 0; r < 4; ++r){
        const int row = m0 + wm*64 + mi*16 + lg*4 + r;
        float v = acc[mi][ni][r] + bc;
        if (RES)  v += resid[(long)row * N + col];
        if (RELU) v = fmaxf(v, 0.f);
        if (OUTBF16) ((unsigned short*)Cout)[(long)row * N + col] = f2bf(v);
        else         ((float*)Cout)[(long)row * N + col] = v;
      }
    }
}

// ---------- V transpose: qkv[.,2048+h*64+dk] -> vt[bh][dk][s] ----------
__global__ __launch_bounds__(256)
void transpose_v(const unsigned short* __restrict__ qkv, unsigned short* __restrict__ vt){
  __shared__ unsigned short tile[64][72];
  const int st = blockIdx.x * 64, bh = blockIdx.y;
  const int b = bh >> 4, h = bh & 15;
  const int tid = threadIdx.x;
  const int r = tid >> 2, c0 = (tid & 3) * 16;
  const unsigned short* src = qkv + ((long)(b*Sc + st + r) * 3072 + 2048 + h*64 + c0);
  *(uint4*)&tile[r][c0]     = *(const uint4*)src;
  *(uint4*)&tile[r][c0 + 8] = *(const uint4*)(src + 8);
  __syncthreads();
  union { unsigned short u[8]; uint4 v; } w0, w1;
#pragma unroll
  for (int j = 0; j < 8; j++){ w0.u[j] = tile[c0 + j][r]; w1.u[j] = tile[c0 + 8 + j][r]; }
  unsigned short* dst = vt + ((long)(bh*64 + r) * Sc + st + c0);
  *(uint4*)dst       = w0.v;
  *(uint4*)(dst + 8) = w1.v;
}

// ---------- flash attention, swapped QK^T, in-lane softmax, l via ones-MFMA ----------
__global__ __launch_bounds__(256)
void attn_k(const unsigned short* __restrict__ qkv, const unsigned short* __restrict__ vt,
            const int* __restrict__ mask, unsigned short* __restrict__ ctx){
  __shared__ unsigned short Qs[64*64], Ks[64*64], Vs[64*64], Ps[4*16*64];
  const int tid = threadIdx.x, wid = tid >> 6, lane = tid & 63;
  const int lg = lane >> 4, lr = lane & 15;
  const int qt = blockIdx.x, bh = blockIdx.y;
  const int b = bh >> 4, h = bh & 15;
  const int s0 = qt * 64;
  const f32x4 zero4 = {0.f, 0.f, 0.f, 0.f};
  const short onebf = (short)0x3F80;
  const bf16x8 ones = {onebf, onebf, onebf, onebf, onebf, onebf, onebf, onebf};

  // stage Q (swizzled source: 16B chunk c holds global chunk c^(r&7))
  const char* qbase = (const char*)qkv + ((long)(b*Sc + s0)) * 6144 + h * 128;
#pragma unroll
  for (int ld = 0; ld < 2; ++ld){
    const int o = (wid*2 + ld) * 1024;
    const int ol = o + lane * 16;
    const int r = ol >> 7, c = (ol >> 4) & 7;
    gload16(qbase + (long)r * 6144 + ((c ^ (r & 7)) << 4), (char*)Qs + o);
  }
  __syncthreads();
  bf16x8 qb[2];
#pragma unroll
  for (int ks = 0; ks < 2; ++ks){
    const int row = wid*16 + lr;
    const int c = ks*4 + lg;
    qb[ks] = *reinterpret_cast<const bf16x8*>((const char*)Qs + row*128 + ((c ^ (row & 7)) << 4));
  }

  float m_ = -1e30f;
  f32x4 acc[4] = {zero4, zero4, zero4, zero4};
  f32x4 accS = zero4;

  const char* kbase = (const char*)qkv + (long)(b*Sc) * 6144 + 2048 + h * 128;
  const char* vbase = (const char*)vt + (long)bh * 64 * 4096;
  const int* mrow = mask + b * Sc;
  unsigned short* pb = Ps + wid * 1024;   // this wave's 16x64 P strip

  for (int t = 0; t < Sc / 64; ++t){
    const int k0 = t * 64;
    int4 mk[4];
#pragma unroll
    for (int ni = 0; ni < 4; ++ni) mk[ni] = *(const int4*)(mrow + k0 + ni*16 + lg*4);

    __syncthreads();   // prev-tile PV LDS reads complete
#pragma unroll
    for (int ld = 0; ld < 2; ++ld){
      const int o = (wid*2 + ld) * 1024;
      const int ol = o + lane * 16;
      const int r = ol >> 7, c = (ol >> 4) & 7;
      const int sw = ((c ^ (r & 7)) << 4);
      gload16(kbase + (long)(k0 + r) * 6144 + sw, (char*)Ks + o);
      gload16(vbase + (long)r * 4096 + k0 * 2 + sw, (char*)Vs + o);
    }
    __syncthreads();

    // S^T = K * Q^T
    f32x4 s4[4];
#pragma unroll
    for (int ni = 0; ni < 4; ++ni){
      s4[ni] = zero4;
      const int row = ni*16 + lr;
#pragma unroll
      for (int ks = 0; ks < 2; ++ks){
        const int c = ks*4 + lg;
        bf16x8 ak = *reinterpret_cast<const bf16x8*>((const char*)Ks + row*128 + ((c ^ (lr & 7)) << 4));
        s4[ni] = mfma16(ak, qb[ks], s4[ni]);
      }
    }
    float p[4][4];
#pragma unroll
    for (int ni = 0; ni < 4; ++ni)
#pragma unroll
      for (int r = 0; r < 4; ++r)
        p[ni][r] = ((&mk[ni].x)[r] != 0) ? s4[ni][r] * 0.125f : -1e9f;

    float mx = fmaxf(fmaxf(p[0][0], p[0][1]), fmaxf(p[0][2], p[0][3]));
#pragma unroll
    for (int ni = 1; ni < 4; ++ni)
      mx = fmaxf(mx, fmaxf(fmaxf(p[ni][0], p[ni][1]), fmaxf(p[ni][2], p[ni][3])));
    mx = fmaxf(mx, __shfl_xor(mx, 16, 64));
    mx = fmaxf(mx, __shfl_xor(mx, 32, 64));

    if (!__all(mx <= m_ + 8.f)){
      const float mnew = fmaxf(m_, mx);
      const float scal = __expf(m_ - mnew);
      m_ = mnew;
      float sr[4];
#pragma unroll
      for (int r = 0; r < 4; ++r) sr[r] = __shfl(scal, lg*4 + r, 64);
#pragma unroll
      for (int ni = 0; ni < 4; ++ni)
#pragma unroll
        for (int r = 0; r < 4; ++r) acc[ni][r] *= sr[r];
#pragma unroll
      for (int r = 0; r < 4; ++r) accS[r] *= sr[r];
    }

#pragma unroll
    for (int ni = 0; ni < 4; ++ni)
#pragma unroll
      for (int r = 0; r < 4; ++r) p[ni][r] = __expf(p[ni][r] - m_);

#pragma unroll
    for (int ni = 0; ni < 4; ++ni){
      uint2 w;
      w.x = pk2bf(p[ni][0], p[ni][1]);
      w.y = pk2bf(p[ni][2], p[ni][3]);
      const int c = ni*2 + (lg >> 1);
      char* dst = (char*)pb + lr*128 + ((c ^ (lr & 7)) << 4) + (lg & 1) * 8;
      *(uint2*)dst = w;
    }
    bf16x8 pa[2];
#pragma unroll
    for (int ks = 0; ks < 2; ++ks){
      const int c = ks*4 + lg;
      pa[ks] = *reinterpret_cast<const bf16x8*>((const char*)pb + lr*128 + ((c ^ (lr & 7)) << 4));
    }
#pragma unroll
    for (int ks = 0; ks < 2; ++ks) accS = mfma16(pa[ks], ones, accS);
#pragma unroll
    for (int ni = 0; ni < 4; ++ni){
      const int row = ni*16 + lr;
#pragma unroll
      for (int ks = 0; ks < 2; ++ks){
        const int c = ks*4 + lg;
        bf16x8 bv8 = *reinterpret_cast<const bf16x8*>((const char*)Vs + row*128 + ((c ^ (lr & 7)) << 4));
        acc[ni] = mfma16(pa[ks], bv8, acc[ni]);
      }
    }
  }
#pragma unroll
  for (int ni = 0; ni < 4; ++ni){
    const int col = h*64 + ni*16 + lr;
#pragma unroll
    for (int r = 0; r < 4; ++r){
      const int row = s0 + wid*16 + lg*4 + r;
      ctx[(long)(b*Sc + row) * Dc + col] = f2bf(acc[ni][r] / accS[r]);
    }
  }
}

// ---------- host ----------
extern "C" void kernel_launch(void* const* d_in, const int* in_sizes, int n_in,
                              void* d_out, int out_size, void* d_ws, size_t ws_size,
                              hipStream_t stream){
  const float* x  = (const float*)d_in[0];
  const int* mask = (const int*)d_in[1];
  const float* wq = (const float*)d_in[2];
  const float* bq = (const float*)d_in[3];
  const float* wk = (const float*)d_in[4];
  const float* bk = (const float*)d_in[5];
  const float* wv = (const float*)d_in[6];
  const float* bv = (const float*)d_in[7];
  const float* wo = (const float*)d_in[8];
  const float* bo = (const float*)d_in[9];
  const float* w1 = (const float*)d_in[10];
  const float* b1 = (const float*)d_in[11];
  const float* w2 = (const float*)d_in[12];
  const float* b2 = (const float*)d_in[13];
  const float* a1 = (const float*)d_in[14];
  const float* g1 = (const float*)d_in[15];
  const float* a2 = (const float*)d_in[16];
  const float* g2 = (const float*)d_in[17];

  if (ws_size < 75509760u) return;   // workspace layout below needs ~75.5 MB

  char* ws = (char*)d_ws;
  unsigned short* wqkv_t = (unsigned short*)(ws + 0);          // [3072][1024]
  unsigned short* wo_t   = (unsigned short*)(ws + 6291456);    // [1024][1024]
  unsigned short* w1_t   = (unsigned short*)(ws + 8388608);    // [4096][1024]
  unsigned short* w2_t   = (unsigned short*)(ws + 16777216);   // [1024][4096]
  float*          bqkv   = (float*)(ws + 25165824);            // [3072]
  unsigned short* nbuf   = (unsigned short*)(ws + 25178112);   // [4096][1024] (n1 then n2)
  unsigned short* qkv    = (unsigned short*)(ws + 33566720);   // [4096][3072]
  unsigned short* ff1    = (unsigned short*)(ws + 33566720);   // [4096][4096] (reuses qkv+vt)
  unsigned short* vt     = (unsigned short*)(ws + 58732544);   // [32][64][2048]
  unsigned short* ctx    = (unsigned short*)(ws + 67121152);   // [4096][1024]
  float* x2 = (float*)d_out;                                   // [4096][1024] f32

  const dim3 tb(32, 8);
  transpose_w<<<dim3(32, 32),  tb, 0, stream>>>(wq, wqkv_t,            1024, 1024);
  transpose_w<<<dim3(32, 32),  tb, 0, stream>>>(wk, wqkv_t + 1048576,  1024, 1024);
  transpose_w<<<dim3(32, 32),  tb, 0, stream>>>(wv, wqkv_t + 2097152,  1024, 1024);
  transpose_w<<<dim3(32, 32),  tb, 0, stream>>>(wo, wo_t,              1024, 1024);
  transpose_w<<<dim3(128, 32), tb, 0, stream>>>(w1, w1_t,              1024, 4096);
  transpose_w<<<dim3(32, 128), tb, 0, stream>>>(w2, w2_t,              4096, 1024);
  concat_bias<<<12, 256, 0, stream>>>(bq, bk, bv, bqkv);

  layernorm_k<<<BSc, 256, 0, stream>>>(x, a1, g1, nbuf);
  gemm256<0,1,0><<<dim3(12, 16), 512, 0, stream>>>(nbuf, wqkv_t, bqkv, nullptr, qkv, BSc, 3072, 1024);
  transpose_v<<<dim3(32, 32), 256, 0, stream>>>(qkv, vt);
  attn_k<<<dim3(32, 32), 256, 0, stream>>>(qkv, vt, mask, ctx);
  gemm128<0,0,1><<<dim3(8, 32), 256, 0, stream>>>(ctx, wo_t, bo, x, x2, BSc, 1024, 1024);
  layernorm_k<<<BSc, 256, 0, stream>>>(x2, a2, g2, nbuf);
  gemm256<1,1,0><<<dim3(16, 16), 512, 0, stream>>>(nbuf, w1_t, b1, nullptr, ff1, BSc, 4096, 1024);
  gemm128<0,0,1><<<dim3(8, 32), 256, 0, stream>>>(ff1, w2_t, b2, x2, d_out, BSc, 1024, 4096);
}